// Round 2
// baseline (207.696 us; speedup 1.0000x reference)
//
#include <hip/hip_runtime.h>

// YOLOv1 loss: pred/label (16384, 30, 7, 7) fp32 -> scalar.
// R8: DMA-pipelined loader. R7 post-mortem: VGPR_Count=32 proved the
// compiler sank all "prefetch" loads to their uses (register staging
// defeated) -> near-serial loads -> 2.7 TB/s pin. Fix: global_load_lds
// DMA (no VGPR destinations, compiler cannot serialize), 12 x 1KB in
// flight per wave, double-buffered per-record pipeline with counted
// s_waitcnt vmcnt(12). Each wave owns 8 records, stages 6KiB pred +
// 6KiB label per record into wave-private LDS, computes from LDS.
// 512 blocks x 256 thr, 96KB LDS/block (1 block/CU by design).

typedef float v2f __attribute__((ext_vector_type(2)));

#define NBATCH 16384
#define RECF   1470                     // floats per record
#define RECB   (RECF * 4)               // 5880 bytes per record
#define BLOCK  256
#define NW     2048                     // total waves
#define GRID   (NW / 4)                 // 512 blocks
#define RPW    (NBATCH / NW)            // 8 records per wave
#define STRIDEF 1536                    // floats per staged tile (6144 B)
#define LIMITB  ((unsigned)NBATCH * RECB - 16u)  // last legal 16B load offset

__device__ __forceinline__ float sq(float x) { return x * x; }

__device__ __forceinline__ void dma16(const float* g, float* l) {
    __builtin_amdgcn_global_load_lds(
        (const __attribute__((address_space(1))) void*)g,
        (__attribute__((address_space(3))) void*)l, 16, 0, 0);
}

// Stage one record (pred+label) into LDS: 12 x 1KB DMAs, fire-and-forget.
// HW semantics: LDS dest = wave-uniform base + lane*16; global src per-lane.
__device__ __forceinline__ void stage_rec(const char* gp, const char* gl,
                                          float* lp, float* ll,
                                          unsigned recOff, unsigned laneB) {
#pragma unroll
    for (int c = 0; c < 6; ++c) {
        unsigned off = recOff + (unsigned)(c * 1024) + laneB;
        if (c == 5) off = (off > LIMITB) ? LIMITB : off;  // buffer-end clamp
        dma16((const float*)(gp + off), lp + c * 256);
        dma16((const float*)(gl + off), ll + c * 256);
    }
}

__device__ __forceinline__ float block_reduce(float v, float* smem, int tid) {
#pragma unroll
    for (int off = 32; off > 0; off >>= 1) v += __shfl_down(v, off, 64);
    const int lane = tid & 63, wave = tid >> 6;
    if (lane == 0) smem[wave] = v;
    __syncthreads();
    return smem[0] + smem[1] + smem[2] + smem[3];
}

__global__ __launch_bounds__(BLOCK) void k_fused(const float* __restrict__ pred,
                                                 const float* __restrict__ label,
                                                 float* __restrict__ partials) {
    // [wave][buf][array: 0=pred 1=label][1536 floats] = 96 KiB
    __shared__ float lds[4][2][2][STRIDEF];
    __shared__ float smem[4];
    const int tid = threadIdx.x, lane = tid & 63, wv = tid >> 6;
    const int gw = blockIdx.x * 4 + wv;          // 0..2047, exact cover
    const unsigned laneB = (unsigned)lane * 16u;
    const char* gp = (const char*)pred;
    const char* gl = (const char*)label;

    float* bP0 = &lds[wv][0][0][0]; float* bL0 = &lds[wv][0][1][0];
    float* bP1 = &lds[wv][1][0][0]; float* bL1 = &lds[wv][1][1][0];

    const int rr = lane / 7, cc = lane - rr * 7;     // valid for lane<49
    const float fr = (float)rr, fcl = (float)cc;
    const float inv7 = 1.0f / 7.0f;
    const int c0 = (2 * lane) % 49;

    float acc = 0.0f;

    // prologue: stage record for t=0 into buffer 0
    stage_rec(gp, gl, bP0, bL0, (unsigned)gw * RECB, laneB);
    __builtin_amdgcn_sched_barrier(0);

    for (int t = 0; t < RPW; ++t) {
        if (t + 1 < RPW) {
            // issue next record into the other buffer, then wait for current
            unsigned nOff = (unsigned)((t + 1) * NW + gw) * RECB;
            float* nP = ((t + 1) & 1) ? bP1 : bP0;
            float* nL = ((t + 1) & 1) ? bL1 : bL0;
            stage_rec(gp, gl, nP, nL, nOff, laneB);
            asm volatile("s_waitcnt vmcnt(12)" ::: "memory");
        } else {
            asm volatile("s_waitcnt vmcnt(0)" ::: "memory");
        }
        __builtin_amdgcn_sched_barrier(0);

        const float* P = (t & 1) ? bP1 : bP0;
        const float* L = (t & 1) ? bL1 : bL0;

        // ---- class term: elementwise from LDS + shfl weights ----
        float w49 = (lane < 49) ? L[196 + lane] : 0.0f;
        int c = c0;
#pragma unroll
        for (int i = 0; i < 8; ++i) {
            int k = i * 64 + lane;                 // float2-pair index, <490
            float d0 = 0.0f, d1 = 0.0f;
            if (k < 490) {
                v2f p2 = *(const v2f*)(P + 490 + 2 * k);
                v2f l2 = *(const v2f*)(L + 490 + 2 * k);
                d0 = p2.x - l2.x; d1 = p2.y - l2.y;
            }
            float w0 = __shfl(w49, c, 64);         // bpermute
            int cn = (c == 48) ? 0 : c + 1;
            float w1 = __shfl(w49, cn, 64);
            acc += w0 * d0 * d0 + w1 * d1 * d1;    // d==0 when k>=490
            c += 30; if (c >= 49) c -= 49;         // m += 128; 128 mod 49 = 30
        }

        // ---- box term: wave-private LDS gather (lanes 0..48) ----
        if (lane < 49) {
            float p[10], l[9];
#pragma unroll
            for (int ch = 0; ch < 10; ++ch) p[ch] = P[ch * 49 + lane];
#pragma unroll
            for (int ch = 0; ch < 9; ++ch) l[ch] = L[ch * 49 + lane];

            float lcx = (l[0] + fcl) * inv7;
            float lcy = (l[1] + fr) * inv7;
            float lhw = l[2] * 0.5f, lhh = l[3] * 0.5f;
            float lx1 = lcx - lhw, ly1 = lcy - lhh;
            float lx2 = lcx + lhw, ly2 = lcy + lhh;
            float larea = (lx2 - lx1) * (ly2 - ly1);

            float cx1 = (p[0] + fcl) * inv7, cy1 = (p[1] + fr) * inv7;
            float x11 = cx1 - p[2] * 0.5f, y11 = cy1 - p[3] * 0.5f;
            float x12 = cx1 + p[2] * 0.5f, y12 = cy1 + p[3] * 0.5f;
            float iw1 = fmaxf(fminf(x12, lx2) - fmaxf(x11, lx1), 0.0f);
            float ih1 = fmaxf(fminf(y12, ly2) - fmaxf(y11, ly1), 0.0f);
            float int1 = iw1 * ih1;
            float a1 = (x12 - x11) * (y12 - y11);
            float iou1 = int1 / (a1 + larea - int1 + 1e-10f);

            float cx2 = (p[5] + fcl) * inv7, cy2 = (p[6] + fr) * inv7;
            float x21 = cx2 - p[7] * 0.5f, y21 = cy2 - p[8] * 0.5f;
            float x22 = cx2 + p[7] * 0.5f, y22 = cy2 + p[8] * 0.5f;
            float iw2 = fmaxf(fminf(x22, lx2) - fmaxf(x21, lx1), 0.0f);
            float ih2 = fmaxf(fminf(y22, ly2) - fmaxf(y21, ly1), 0.0f);
            float int2 = iw2 * ih2;
            float a2 = (x22 - x21) * (y22 - y21);
            float iou2 = int2 / (a2 + larea - int2 + 1e-10f);

            bool ch1 = iou1 >= iou2;

            float coord1 = 5.0f * (sq(p[0] - l[0]) + sq(p[1] - l[1]))
                         + sq(sqrtf(p[2]) - sqrtf(l[2])) + sq(sqrtf(p[3]) - sqrtf(l[3]));
            float coord2 = 5.0f * (sq(p[5] - l[5]) + sq(p[6] - l[6]))
                         + sq(sqrtf(p[7]) - sqrtf(l[7])) + sq(sqrtf(p[8]) - sqrtf(l[8]));
            float obj1 = sq(p[4] - iou1);
            float obj2 = sq(p[9] - iou2);

            float obj_cell = (ch1 ? coord1 : coord2)
                           + (ch1 ? obj1 : obj2)
                           + 0.5f * (ch1 ? obj2 : obj1);   // class term added above
            float noobj_cell = 0.5f * sq(p[4] + p[9]);

            acc += (l[4] == 1.0f) ? obj_cell : noobj_cell;
        }
    }

    float s = block_reduce(acc, smem, tid);
    if (tid == 0) partials[blockIdx.x] = s;
}

// ---------------- final reduce: 512 partials ----------------
__global__ __launch_bounds__(BLOCK) void k_reduce(const float* __restrict__ partials,
                                                  float* __restrict__ out) {
    __shared__ float smem[4];
    float s = 0.0f;
#pragma unroll
    for (int it = 0; it < GRID / BLOCK; ++it)   // 2 independent loads
        s += partials[it * BLOCK + threadIdx.x];
    float t = block_reduce(s, smem, threadIdx.x);
    if (threadIdx.x == 0) out[0] = t * (1.0f / (float)NBATCH);
}

extern "C" void kernel_launch(void* const* d_in, const int* in_sizes, int n_in,
                              void* d_out, int out_size, void* d_ws, size_t ws_size,
                              hipStream_t stream) {
    const float* pred  = (const float*)d_in[0];
    const float* label = (const float*)d_in[1];
    float* out = (float*)d_out;
    float* part = (float*)d_ws;          // 512 floats

    k_fused<<<GRID, BLOCK, 0, stream>>>(pred, label, part);
    k_reduce<<<1, BLOCK, 0, stream>>>(part, out);
}

// Round 3
// 204.887 us; speedup vs baseline: 1.0137x; 1.0137x over previous
//
#include <hip/hip_runtime.h>

// YOLOv1 loss: pred/label (16384, 30, 7, 7) fp32 -> scalar.
// R9: copy-ubench-shaped loader. R6/R7/R8 (split-stream, reg-fused,
// 12-deep global_load_lds DMA) ALL pin at 2.4-2.7 TB/s read with pipes
// idle => service-rate cap, not MLP. Only >3 TB/s read evidence on this
// chip is the float4-copy ubench (16B/lane dwordx4). Reproduce it:
// block-per-2-records, 6 independent dwordx4/thread (16B/lane, ~147 KB/CU
// in flight), stage 23.5 KB to LDS, compute class+box from LDS.
// Pre-commit: unchanged ~75us => read roofline (~1 rd-req/cy/XCD model).

typedef float v2f __attribute__((ext_vector_type(2)));
typedef float v4f __attribute__((ext_vector_type(4)));

#define NBATCH 16384
#define RECF   1470              // floats per record
#define BLOCK  256
#define GRID   (NBATCH / 2)      // 8192 blocks, 2 records per block
#define BLKF4  735               // float4s per tensor per block (2*1470/4)

__device__ __forceinline__ float sq(float x) { return x * x; }

__device__ __forceinline__ float block_reduce(float v, float* smem, int tid) {
#pragma unroll
    for (int off = 32; off > 0; off >>= 1) v += __shfl_down(v, off, 64);
    const int lane = tid & 63, wave = tid >> 6;
    if (lane == 0) smem[wave] = v;
    __syncthreads();
    return smem[0] + smem[1] + smem[2] + smem[3];
}

__global__ __launch_bounds__(BLOCK) void k_fused(const float* __restrict__ pred,
                                                 const float* __restrict__ label,
                                                 float* __restrict__ partials) {
    __shared__ __align__(16) float lp[2 * RECF];   // 2940 floats: pred, 2 records
    __shared__ __align__(16) float ll[2 * RECF];   // 2940 floats: label
    __shared__ float smem[4];
    const int tid = threadIdx.x, lane = tid & 63, wv = tid >> 6;

    // 2940*b floats = 735*b float4s: always 16B-aligned slice start.
    const v4f* gp4 = (const v4f*)pred  + (size_t)blockIdx.x * BLKF4;
    const v4f* gl4 = (const v4f*)label + (size_t)blockIdx.x * BLKF4;

    // ---- stage both records: 6 independent dwordx4 per thread ----
    const int i0 = tid, i1 = tid + 256, i2 = tid + 512;
    const int i2c = (i2 < BLKF4) ? i2 : (BLKF4 - 1);   // clamp: no OOB on last block
    v4f p0 = gp4[i0];  v4f l0 = gl4[i0];
    v4f p1 = gp4[i1];  v4f l1 = gl4[i1];
    v4f p2 = gp4[i2c]; v4f l2 = gl4[i2c];
    ((v4f*)lp)[i0] = p0; ((v4f*)ll)[i0] = l0;
    ((v4f*)lp)[i1] = p1; ((v4f*)ll)[i1] = l1;
    if (i2 < BLKF4) { ((v4f*)lp)[i2] = p2; ((v4f*)ll)[i2] = l2; }
    __syncthreads();

    // wave -> (record, class-half); the sub==1 wave also does the box term
    const int rec = wv >> 1, sub = wv & 1;
    const float* P = lp + rec * RECF;
    const float* L = ll + rec * RECF;

    float acc = 0.0f;

    // ---- class term: 490 float2-pairs, two waves interleaved by 64 ----
    // element j=2k in channel-major class region; cell c=(2k)%49; weight
    // gathered straight from LDS label[196+c] (exactly 0.0/1.0).
    int c = (2 * (sub * 64 + lane)) % 49;
#pragma unroll
    for (int i = 0; i < 4; ++i) {
        int k = i * 128 + sub * 64 + lane;
        if (k < 490) {
            v2f pp = *(const v2f*)(P + 490 + 2 * k);
            v2f lq = *(const v2f*)(L + 490 + 2 * k);
            float w0 = L[196 + c];
            int cn = (c == 48) ? 0 : c + 1;
            float w1 = L[196 + cn];
            float d0 = pp.x - lq.x, d1 = pp.y - lq.y;
            acc += w0 * d0 * d0 + w1 * d1 * d1;
        }
        c += 11; if (c >= 49) c -= 49;   // k += 128 -> 2k += 256; 256 mod 49 = 11
    }

    // ---- box term: lanes 0..48 of the sub==1 wave ----
    if (sub == 1 && lane < 49) {
        const int rr = lane / 7, cc = lane - rr * 7;
        const float fr = (float)rr, fcl = (float)cc;
        const float inv7 = 1.0f / 7.0f;

        float p[10], l[9];
#pragma unroll
        for (int ch = 0; ch < 10; ++ch) p[ch] = P[ch * 49 + lane];
#pragma unroll
        for (int ch = 0; ch < 9; ++ch) l[ch] = L[ch * 49 + lane];

        float lcx = (l[0] + fcl) * inv7;
        float lcy = (l[1] + fr) * inv7;
        float lhw = l[2] * 0.5f, lhh = l[3] * 0.5f;
        float lx1 = lcx - lhw, ly1 = lcy - lhh;
        float lx2 = lcx + lhw, ly2 = lcy + lhh;
        float larea = (lx2 - lx1) * (ly2 - ly1);

        float cx1 = (p[0] + fcl) * inv7, cy1 = (p[1] + fr) * inv7;
        float x11 = cx1 - p[2] * 0.5f, y11 = cy1 - p[3] * 0.5f;
        float x12 = cx1 + p[2] * 0.5f, y12 = cy1 + p[3] * 0.5f;
        float iw1 = fmaxf(fminf(x12, lx2) - fmaxf(x11, lx1), 0.0f);
        float ih1 = fmaxf(fminf(y12, ly2) - fmaxf(y11, ly1), 0.0f);
        float int1 = iw1 * ih1;
        float a1 = (x12 - x11) * (y12 - y11);
        float iou1 = int1 / (a1 + larea - int1 + 1e-10f);

        float cx2 = (p[5] + fcl) * inv7, cy2 = (p[6] + fr) * inv7;
        float x21 = cx2 - p[7] * 0.5f, y21 = cy2 - p[8] * 0.5f;
        float x22 = cx2 + p[7] * 0.5f, y22 = cy2 + p[8] * 0.5f;
        float iw2 = fmaxf(fminf(x22, lx2) - fmaxf(x21, lx1), 0.0f);
        float ih2 = fmaxf(fminf(y22, ly2) - fmaxf(y21, ly1), 0.0f);
        float int2 = iw2 * ih2;
        float a2 = (x22 - x21) * (y22 - y21);
        float iou2 = int2 / (a2 + larea - int2 + 1e-10f);

        bool ch1 = iou1 >= iou2;

        float coord1 = 5.0f * (sq(p[0] - l[0]) + sq(p[1] - l[1]))
                     + sq(sqrtf(p[2]) - sqrtf(l[2])) + sq(sqrtf(p[3]) - sqrtf(l[3]));
        float coord2 = 5.0f * (sq(p[5] - l[5]) + sq(p[6] - l[6]))
                     + sq(sqrtf(p[7]) - sqrtf(l[7])) + sq(sqrtf(p[8]) - sqrtf(l[8]));
        float obj1 = sq(p[4] - iou1);
        float obj2 = sq(p[9] - iou2);

        float obj_cell = (ch1 ? coord1 : coord2)
                       + (ch1 ? obj1 : obj2)
                       + 0.5f * (ch1 ? obj2 : obj1);   // class term added above
        float noobj_cell = 0.5f * sq(p[4] + p[9]);

        acc += (l[4] == 1.0f) ? obj_cell : noobj_cell;
    }

    float s = block_reduce(acc, smem, tid);
    if (tid == 0) partials[blockIdx.x] = s;
}

// ---------------- final reduce: 8192 partials ----------------
__global__ __launch_bounds__(BLOCK) void k_reduce(const float* __restrict__ partials,
                                                  float* __restrict__ out) {
    __shared__ float smem[4];
    float s = 0.0f;
#pragma unroll
    for (int it = 0; it < GRID / BLOCK; ++it)   // 32 independent loads
        s += partials[it * BLOCK + threadIdx.x];
    float t = block_reduce(s, smem, threadIdx.x);
    if (threadIdx.x == 0) out[0] = t * (1.0f / (float)NBATCH);
}

extern "C" void kernel_launch(void* const* d_in, const int* in_sizes, int n_in,
                              void* d_out, int out_size, void* d_ws, size_t ws_size,
                              hipStream_t stream) {
    const float* pred  = (const float*)d_in[0];
    const float* label = (const float*)d_in[1];
    float* out = (float*)d_out;
    float* part = (float*)d_ws;          // 8192 floats

    k_fused<<<GRID, BLOCK, 0, stream>>>(pred, label, part);
    k_reduce<<<1, BLOCK, 0, stream>>>(part, out);
}